// Round 1
// baseline (168.141 us; speedup 1.0000x reference)
//
#include <hip/hip_runtime.h>

// Sector4Pooling2D: out[b,h,w, q*64+c] = x[b, h+(q>>1)*112, w+(q&1)*112, c]
// B=32, H=W=224, C=64, d1=d2=112. Pure permutation copy, memory-bound.

__global__ __launch_bounds__(256) void sector4_kernel(
    const float4* __restrict__ in, float4* __restrict__ out, int total4) {
    int stride = gridDim.x * blockDim.x;
    for (int i = blockIdx.x * blockDim.x + threadIdx.x; i < total4; i += stride) {
        // Output linear float4 index decomposition:
        //   out float4s per pixel = 256 floats / 4 = 64
        int c4  = i & 63;        // which float4 within the 256-channel output pixel
        int pix = i >> 6;        // b*112*112 + h*112 + w
        int w = pix % 112;
        int t = pix / 112;
        int h = t % 112;
        int b = t / 112;
        int q = c4 >> 4;         // quadrant 0..3 (16 float4 = 64 floats each)
        int c = c4 & 15;         // float4 index within source channel dim
        int H = h + ((q >> 1) * 112);
        int W = w + ((q & 1) * 112);
        // src float4 index: ((b*224 + H)*224 + W)*16 + c   (64 floats = 16 float4 per src pixel)
        int src = (((b * 224 + H) * 224 + W) << 4) + c;
        out[i] = in[src];
    }
}

extern "C" void kernel_launch(void* const* d_in, const int* in_sizes, int n_in,
                              void* d_out, int out_size, void* d_ws, size_t ws_size,
                              hipStream_t stream) {
    const float4* x = (const float4*)d_in[0];
    float4* out = (float4*)d_out;
    int total4 = out_size / 4;   // 25,690,112 float4s
    int block = 256;
    int grid = 2048;             // 256 CU * 8 blocks; grid-stride covers the rest
    sector4_kernel<<<grid, block, 0, stream>>>(x, out, total4);
}

// Round 3
// 128.838 us; speedup vs baseline: 1.3050x; 1.3050x over previous
//
#include <hip/hip_runtime.h>

// Sector4Pooling2D: out[b,h,w, q*64+c] = x[b, h+(q>>1)*112, w+(q&1)*112, c]
// B=32, H=W=224, C=64, d1=d2=112. Pure permutation copy, memory-bound.
//
// Grid: blockIdx.y = b*112 + h (3584 rows), blockIdx.x covers the 7168
// float4s of one output row (w in [0,112) x c4 in [0,64)). One float4 per
// thread, no per-lane division (b,h derived from uniform blockIdx.y on the
// scalar unit). Wave64 reads 4x256B contiguous, writes 1KB contiguous.
// Nontemporal hints: 822MB streamed, nothing reused.

typedef float vfloat4 __attribute__((ext_vector_type(4)));

__global__ __launch_bounds__(256) void sector4_kernel(
    const vfloat4* __restrict__ in, vfloat4* __restrict__ out) {
    int j   = blockIdx.x * 256 + threadIdx.x;  // 0..7167 within output row
    int row = blockIdx.y;                      // b*112 + h  (uniform)
    int c4 = j & 63;    // float4 index within 256-ch output pixel
    int w  = j >> 6;    // 0..111
    int q  = c4 >> 4;   // quadrant
    int c  = c4 & 15;   // float4 within 64-ch source pixel
    int b  = row / 112; // uniform -> scalar magic-mul
    int h  = row - b * 112;
    int H = h + ((q >> 1) * 112);
    int W = w + ((q & 1) * 112);
    int src = (((b * 224 + H) * 224 + W) << 4) + c;
    int dst = row * 7168 + j;
    vfloat4 v = __builtin_nontemporal_load(&in[src]);
    __builtin_nontemporal_store(v, &out[dst]);
}

extern "C" void kernel_launch(void* const* d_in, const int* in_sizes, int n_in,
                              void* d_out, int out_size, void* d_ws, size_t ws_size,
                              hipStream_t stream) {
    const vfloat4* x = (const vfloat4*)d_in[0];
    vfloat4* out = (vfloat4*)d_out;
    dim3 grid(28, 3584);   // 28*256 = 7168 float4/row; 3584 = 32*112 rows
    sector4_kernel<<<grid, 256, 0, stream>>>(x, out);
}